// Round 2
// baseline (81.507 us; speedup 1.0000x reference)
//
#include <hip/hip_runtime.h>

#define DH 40
#define DW 40
#define DT 40
#define NC 96
#define NH 6
#define HD 16
#define NTOK 27
#define NVOX (DH * DW * DT)

#define NXCD 8
#define SLABX 5                          // x-planes per XCD slab (40/8)
#define SLAB_THREADS (SLABX * DW * DT * NH)   // 48000
#define BLOCKS_PER_SLAB ((SLAB_THREADS + 255) / 256)  // 188

__global__ __launch_bounds__(256) void natt_disp_kernel(
    const float* __restrict__ q,
    const float* __restrict__ k,
    const float* __restrict__ rpb,
    float* __restrict__ out)
{
    __shared__ float s_rpb[NH * NTOK];
    if (threadIdx.x < NH * NTOK) s_rpb[threadIdx.x] = rpb[threadIdx.x];
    __syncthreads();

    // XCD-slab mapping: consecutive blockIdx round-robin across XCDs, so
    // blockIdx % 8 selects the XCD; give each XCD a contiguous x-slab.
    const int xcd = blockIdx.x & (NXCD - 1);
    const int c   = blockIdx.x >> 3;
    const int lid = c * 256 + threadIdx.x;
    if (lid >= SLAB_THREADS) return;

    const int h  = lid % NH;
    const int vl = lid / NH;             // local voxel in slab, z-fastest
    const int z  = vl % DT;
    const int y  = (vl / DT) % DW;
    const int x  = xcd * SLABX + vl / (DT * DW);
    const int vox = (x * DW + y) * DT + z;

    const float scale = 0.25f;  // 16^-0.5

    const float4* qv = (const float4*)(q + (size_t)vox * NC + h * HD);
    float4 q0 = qv[0], q1 = qv[1], q2 = qv[2], q3 = qv[3];
    q0.x *= scale; q0.y *= scale; q0.z *= scale; q0.w *= scale;
    q1.x *= scale; q1.y *= scale; q1.z *= scale; q1.w *= scale;
    q2.x *= scale; q2.y *= scale; q2.z *= scale; q2.w *= scale;
    q3.x *= scale; q3.y *= scale; q3.z *= scale; q3.w *= scale;

    const float* kh = k + h * HD;

    float logits[NTOK];

    // Branchless: clamp coords (always a valid address), mask the dot.
    #pragma unroll
    for (int i = 0; i < 3; ++i) {
        #pragma unroll
        for (int j = 0; j < 3; ++j) {
            #pragma unroll
            for (int l = 0; l < 3; ++l) {
                const int kk = (i * 3 + j) * 3 + l;
                const int xr = x + i - 1;
                const int yr = y + j - 1;
                const int zr = z + l - 1;
                const bool valid = ((unsigned)xr < DH) & ((unsigned)yr < DW)
                                 & ((unsigned)zr < DT);
                const int xx = min(max(xr, 0), DH - 1);
                const int yy = min(max(yr, 0), DW - 1);
                const int zz = min(max(zr, 0), DT - 1);
                const float4* kv = (const float4*)(
                    kh + ((size_t)((xx * DW + yy) * DT + zz)) * NC);
                float4 k0 = kv[0], k1 = kv[1], k2 = kv[2], k3 = kv[3];
                float dot = q0.x * k0.x + q0.y * k0.y + q0.z * k0.z + q0.w * k0.w
                          + q1.x * k1.x + q1.y * k1.y + q1.z * k1.z + q1.w * k1.w
                          + q2.x * k2.x + q2.y * k2.y + q2.z * k2.z + q2.w * k2.w
                          + q3.x * k3.x + q3.y * k3.y + q3.z * k3.z + q3.w * k3.w;
                logits[kk] = (valid ? dot : 0.0f) + s_rpb[h * NTOK + kk];
            }
        }
    }

    float m = logits[0];
    #pragma unroll
    for (int kk = 1; kk < NTOK; ++kk) m = fmaxf(m, logits[kk]);
    float sum = 0.0f;
    #pragma unroll
    for (int kk = 0; kk < NTOK; ++kk) {
        float e = __expf(logits[kk] - m);
        logits[kk] = e;
        sum += e;
    }
    const float inv = 1.0f / sum;

    float sx = 0.0f, sy = 0.0f, sz = 0.0f;
    #pragma unroll
    for (int i = 0; i < 3; ++i) {
        #pragma unroll
        for (int j = 0; j < 3; ++j) {
            #pragma unroll
            for (int l = 0; l < 3; ++l) {
                const float a = logits[(i * 3 + j) * 3 + l];
                sx += a * (float)(i - 1);
                sy += a * (float)(j - 1);
                sz += a * (float)(l - 1);
            }
        }
    }
    sx *= inv; sy *= inv; sz *= inv;

    out[((size_t)(h * 3 + 0)) * NVOX + vox] = sx;
    out[((size_t)(h * 3 + 1)) * NVOX + vox] = sy;
    out[((size_t)(h * 3 + 2)) * NVOX + vox] = sz;
}

extern "C" void kernel_launch(void* const* d_in, const int* in_sizes, int n_in,
                              void* d_out, int out_size, void* d_ws, size_t ws_size,
                              hipStream_t stream) {
    const float* q   = (const float*)d_in[0];
    const float* k   = (const float*)d_in[1];
    const float* rpb = (const float*)d_in[2];
    float* out = (float*)d_out;

    const int grid = NXCD * BLOCKS_PER_SLAB;   // 1504 blocks
    natt_disp_kernel<<<grid, 256, 0, stream>>>(q, k, rpb, out);
}

// Round 3
// 35.901 us; speedup vs baseline: 2.2703x; 2.2703x over previous
//
#include <hip/hip_runtime.h>

#define DH 40
#define DW 40
#define DT 40
#define NC 96
#define NH 6
#define HD 16
#define NTOK 27
#define NVOX (DH * DW * DT)

// Tile geometry: block = one head x (8 x 4 x 8) voxel tile, 256 threads.
#define TX 8
#define TY 4
#define TZ 8
#define HX 10
#define HY 6
#define HZ 10
#define NHALO (HX * HY * HZ)      // 600 halo voxels
#define KSTRIDE 20                // dwords per voxel in LDS (padded from 16)

#define TXN (DH / TX)             // 5
#define TYN (DW / TY)             // 10
#define TZN (DT / TZ)             // 5
#define NTILE (TXN * TYN * TZN)   // 250
#define NJOB (NTILE * NH)         // 1500
#define NXCD 8
#define GRID 1504                 // padded to multiple of 8
#define PER_XCD (GRID / NXCD)     // 188

__global__ __launch_bounds__(256) void natt_disp_kernel(
    const float* __restrict__ q,
    const float* __restrict__ k,
    const float* __restrict__ rpb,
    float* __restrict__ out)
{
    __shared__ float s_k[NHALO * KSTRIDE];   // 48 KB
    __shared__ float s_q[TX * TY * TZ * KSTRIDE]; // 20.5 KB
    __shared__ float s_rpb[NTOK];

    // XCD swizzle: blocks round-robin across 8 XCDs; give each XCD a
    // contiguous job chunk so the 6 head-blocks of a tile (and z-adjacent
    // tiles) share one L2.
    const int job = (blockIdx.x & (NXCD - 1)) * PER_XCD + (blockIdx.x >> 3);
    if (job >= NJOB) return;   // block-uniform, before any __syncthreads

    const int h    = job % NH;
    const int tile = job / NH;
    const int tz = tile % TZN;
    const int ty = (tile / TZN) % TYN;
    const int tx = tile / (TZN * TYN);
    const int x0 = tx * TX, y0 = ty * TY, z0 = tz * TZ;

    const int tid = threadIdx.x;

    if (tid < NTOK) s_rpb[tid] = rpb[h * NTOK + tid];

    // ---- Stage k halo: 600 voxels x 4 float4 chunks = 2400 jobs ----
    #pragma unroll
    for (int it = 0; it < 10; ++it) {
        const int f = tid + it * 256;
        if (f < NHALO * 4) {
            const int n = f >> 2;
            const int c = f & 3;
            const int hx = n / (HY * HZ);
            const int r  = n % (HY * HZ);
            const int hy = r / HZ;
            const int hz = r % HZ;
            const int gx = x0 - 1 + hx;
            const int gy = y0 - 1 + hy;
            const int gz = z0 - 1 + hz;
            float4 v = make_float4(0.f, 0.f, 0.f, 0.f);
            if (((unsigned)gx < DH) & ((unsigned)gy < DW) & ((unsigned)gz < DT)) {
                v = *(const float4*)(k + ((size_t)((gx * DW + gy) * DT + gz)) * NC
                                       + h * HD + c * 4);
            }
            *(float4*)&s_k[n * KSTRIDE + c * 4] = v;
        }
    }

    // ---- Stage q tile: 256 voxels x 4 chunks = 1024 jobs ----
    #pragma unroll
    for (int it = 0; it < 4; ++it) {
        const int f = tid + it * 256;
        const int n = f >> 2;
        const int c = f & 3;
        const int lz = n & (TZ - 1);
        const int ly = (n >> 3) & (TY - 1);
        const int lx = n >> 5;
        const int gvox = ((x0 + lx) * DW + (y0 + ly)) * DT + (z0 + lz);
        float4 v = *(const float4*)(q + (size_t)gvox * NC + h * HD + c * 4);
        *(float4*)&s_q[n * KSTRIDE + c * 4] = v;
    }

    __syncthreads();

    // ---- Compute: thread = one voxel of the tile ----
    const int lz = tid & (TZ - 1);
    const int ly = (tid >> 3) & (TY - 1);
    const int lx = tid >> 5;

    const float4* qv = (const float4*)&s_q[tid * KSTRIDE];
    const float4 q0 = qv[0], q1 = qv[1], q2 = qv[2], q3 = qv[3];

    float acc[NTOK];

    #pragma unroll
    for (int i = 0; i < 3; ++i) {
        #pragma unroll
        for (int j = 0; j < 3; ++j) {
            const int base = ((lx + i) * HY + (ly + j)) * HZ + lz;
            #pragma unroll
            for (int l = 0; l < 3; ++l) {
                const float4* kv = (const float4*)&s_k[(base + l) * KSTRIDE];
                const float4 k0 = kv[0], k1 = kv[1], k2 = kv[2], k3 = kv[3];
                float d;
                d  = q0.x * k0.x + q0.y * k0.y + q0.z * k0.z + q0.w * k0.w;
                d += q1.x * k1.x + q1.y * k1.y + q1.z * k1.z + q1.w * k1.w;
                d += q2.x * k2.x + q2.y * k2.y + q2.z * k2.z + q2.w * k2.w;
                d += q3.x * k3.x + q3.y * k3.y + q3.z * k3.z + q3.w * k3.w;
                acc[(i * 3 + j) * 3 + l] = d;
            }
        }
    }

    const float scale = 0.25f;  // 16^-0.5
    float logits[NTOK];
    #pragma unroll
    for (int kk = 0; kk < NTOK; ++kk)
        logits[kk] = fmaf(acc[kk], scale, s_rpb[kk]);

    float m = logits[0];
    #pragma unroll
    for (int kk = 1; kk < NTOK; ++kk) m = fmaxf(m, logits[kk]);
    float sum = 0.0f;
    #pragma unroll
    for (int kk = 0; kk < NTOK; ++kk) {
        const float e = __expf(logits[kk] - m);
        logits[kk] = e;
        sum += e;
    }
    const float inv = 1.0f / sum;

    float sx = 0.f, sy = 0.f, sz = 0.f;
    #pragma unroll
    for (int i = 0; i < 3; ++i) {
        #pragma unroll
        for (int j = 0; j < 3; ++j) {
            #pragma unroll
            for (int l = 0; l < 3; ++l) {
                const float a = logits[(i * 3 + j) * 3 + l];
                sx += a * (float)(i - 1);
                sy += a * (float)(j - 1);
                sz += a * (float)(l - 1);
            }
        }
    }
    sx *= inv; sy *= inv; sz *= inv;

    const int vox = ((x0 + lx) * DW + (y0 + ly)) * DT + (z0 + lz);
    out[((size_t)(h * 3 + 0)) * NVOX + vox] = sx;
    out[((size_t)(h * 3 + 1)) * NVOX + vox] = sy;
    out[((size_t)(h * 3 + 2)) * NVOX + vox] = sz;
}

extern "C" void kernel_launch(void* const* d_in, const int* in_sizes, int n_in,
                              void* d_out, int out_size, void* d_ws, size_t ws_size,
                              hipStream_t stream) {
    const float* q   = (const float*)d_in[0];
    const float* k   = (const float*)d_in[1];
    const float* rpb = (const float*)d_in[2];
    float* out = (float*)d_out;

    natt_disp_kernel<<<GRID, 256, 0, stream>>>(q, k, rpb, out);
}

// Round 4
// 22.621 us; speedup vs baseline: 3.6031x; 1.5871x over previous
//
#include <hip/hip_runtime.h>

typedef _Float16 h2 __attribute__((ext_vector_type(2)));

#define DH 40
#define DW 40
#define DT 40
#define NC 96
#define NH 6
#define HD 16
#define NTOK 27
#define NVOX (DH * DW * DT)

// Tile: one head x (8 x 4 x 8) voxels, 256 threads, thread = 1 voxel.
#define TX 8
#define TY 4
#define TZ 8
#define HX 10
#define HY 6
#define HZ 10
#define NHALO (HX * HY * HZ)       // 600
// LDS k layout: f16, row = 16 f16 = 2 int4 chunks + 1 int4 pad (stride 3 int4
// = 12 dwords; z-lane bank starts n*12 mod 32 cover all 8 slots).
#define ROW_I4 3

#define TXN (DH / TX)              // 5
#define TYN (DW / TY)              // 10
#define TZN (DT / TZ)              // 5
#define NTILE (TXN * TYN * TZN)    // 250
#define NJOB (NTILE * NH)          // 1500
#define NXCD 8
#define GRID 1504
#define PER_XCD (GRID / NXCD)      // 188

#if defined(__has_builtin)
#if __has_builtin(__builtin_amdgcn_fdot2)
#define HAVE_FDOT2 1
#endif
#endif

__device__ __forceinline__ float dot2acc(h2 a, h2 b, float c) {
#ifdef HAVE_FDOT2
    return __builtin_amdgcn_fdot2(a, b, c, false);
#else
    return c + (float)a.x * (float)b.x + (float)a.y * (float)b.y;
#endif
}

union I4H {
    int4 v;
    h2 h[4];
};

__global__ __launch_bounds__(256) void natt_disp_kernel(
    const float* __restrict__ q,
    const float* __restrict__ k,
    const float* __restrict__ rpb,
    float* __restrict__ out)
{
    __shared__ int4 s_k[NHALO * ROW_I4];   // 28.8 KB
    __shared__ float s_rpb[NTOK];

    // XCD swizzle: consecutive blockIdx round-robin across 8 XCDs; chunk the
    // job space so each XCD gets contiguous jobs (6 heads of a tile adjacent
    // -> shared k/q lines live in one L2).
    const int job = (blockIdx.x & (NXCD - 1)) * PER_XCD + (blockIdx.x >> 3);
    if (job >= NJOB) return;   // uniform per block, before any sync

    const int h    = job % NH;
    const int tile = job / NH;
    const int tz = tile % TZN;
    const int ty = (tile / TZN) % TYN;
    const int tx = tile / (TZN * TYN);
    const int x0 = tx * TX, y0 = ty * TY, z0 = tz * TZ;

    const int tid = threadIdx.x;

    if (tid < NTOK) s_rpb[tid] = rpb[h * NTOK + tid];

    // ---- Stage k halo as f16: 600 vectors x 2 half-chunks = 1200 jobs ----
    #pragma unroll
    for (int it = 0; it < 5; ++it) {
        const int f = tid + it * 256;
        if (f < NHALO * 2) {
            const int n    = f >> 1;
            const int half = f & 1;
            const int hx = n / (HY * HZ);
            const int r  = n % (HY * HZ);
            const int hy = r / HZ;
            const int hz = r % HZ;
            const int gx = x0 - 1 + hx;
            const int gy = y0 - 1 + hy;
            const int gz = z0 - 1 + hz;
            I4H u;
            u.v = make_int4(0, 0, 0, 0);
            if (((unsigned)gx < DH) & ((unsigned)gy < DW) & ((unsigned)gz < DT)) {
                const float* src = k + ((size_t)((gx * DW + gy) * DT + gz)) * NC
                                     + h * HD + half * 8;
                const float4 a = *(const float4*)(src);
                const float4 b = *(const float4*)(src + 4);
                u.h[0] = h2{(_Float16)a.x, (_Float16)a.y};
                u.h[1] = h2{(_Float16)a.z, (_Float16)a.w};
                u.h[2] = h2{(_Float16)b.x, (_Float16)b.y};
                u.h[3] = h2{(_Float16)b.z, (_Float16)b.w};
            }
            s_k[n * ROW_I4 + half] = u.v;
        }
    }

    // ---- q fragment direct (one full 64B line per lane), scale folded ----
    const int lz = tid & (TZ - 1);
    const int ly = (tid >> 3) & (TY - 1);
    const int lx = tid >> 5;
    const int vox = ((x0 + lx) * DW + (y0 + ly)) * DT + (z0 + lz);

    const float scale = 0.25f;  // 16^-0.5
    h2 qh[8];
    {
        const float4* qv = (const float4*)(q + (size_t)vox * NC + h * HD);
        const float4 a = qv[0], b = qv[1], c = qv[2], d = qv[3];
        qh[0] = h2{(_Float16)(a.x * scale), (_Float16)(a.y * scale)};
        qh[1] = h2{(_Float16)(a.z * scale), (_Float16)(a.w * scale)};
        qh[2] = h2{(_Float16)(b.x * scale), (_Float16)(b.y * scale)};
        qh[3] = h2{(_Float16)(b.z * scale), (_Float16)(b.w * scale)};
        qh[4] = h2{(_Float16)(c.x * scale), (_Float16)(c.y * scale)};
        qh[5] = h2{(_Float16)(c.z * scale), (_Float16)(c.w * scale)};
        qh[6] = h2{(_Float16)(d.x * scale), (_Float16)(d.y * scale)};
        qh[7] = h2{(_Float16)(d.z * scale), (_Float16)(d.w * scale)};
    }

    __syncthreads();

    // ---- 27 neighbor dots: 2x ds_read_b128 + 8x v_dot2_f32_f16 each ----
    float logits[NTOK];
    #pragma unroll
    for (int i = 0; i < 3; ++i) {
        #pragma unroll
        for (int j = 0; j < 3; ++j) {
            const int base = ((lx + i) * HY + (ly + j)) * HZ + lz;
            #pragma unroll
            for (int l = 0; l < 3; ++l) {
                const int n = base + l;
                I4H u0, u1;
                u0.v = s_k[n * ROW_I4 + 0];
                u1.v = s_k[n * ROW_I4 + 1];
                float d = 0.0f;
                d = dot2acc(qh[0], u0.h[0], d);
                d = dot2acc(qh[1], u0.h[1], d);
                d = dot2acc(qh[2], u0.h[2], d);
                d = dot2acc(qh[3], u0.h[3], d);
                d = dot2acc(qh[4], u1.h[0], d);
                d = dot2acc(qh[5], u1.h[1], d);
                d = dot2acc(qh[6], u1.h[2], d);
                d = dot2acc(qh[7], u1.h[3], d);
                logits[(i * 3 + j) * 3 + l] = d + s_rpb[(i * 3 + j) * 3 + l];
            }
        }
    }

    // ---- softmax over 27 ----
    float m = logits[0];
    #pragma unroll
    for (int kk = 1; kk < NTOK; ++kk) m = fmaxf(m, logits[kk]);
    float sum = 0.0f;
    #pragma unroll
    for (int kk = 0; kk < NTOK; ++kk) {
        const float e = __expf(logits[kk] - m);
        logits[kk] = e;
        sum += e;
    }
    const float inv = 1.0f / sum;

    // ---- expected displacement ----
    float sx = 0.f, sy = 0.f, sz = 0.f;
    #pragma unroll
    for (int i = 0; i < 3; ++i) {
        #pragma unroll
        for (int j = 0; j < 3; ++j) {
            #pragma unroll
            for (int l = 0; l < 3; ++l) {
                const float a = logits[(i * 3 + j) * 3 + l];
                sx += a * (float)(i - 1);
                sy += a * (float)(j - 1);
                sz += a * (float)(l - 1);
            }
        }
    }
    sx *= inv; sy *= inv; sz *= inv;

    out[((size_t)(h * 3 + 0)) * NVOX + vox] = sx;
    out[((size_t)(h * 3 + 1)) * NVOX + vox] = sy;
    out[((size_t)(h * 3 + 2)) * NVOX + vox] = sz;
}

extern "C" void kernel_launch(void* const* d_in, const int* in_sizes, int n_in,
                              void* d_out, int out_size, void* d_ws, size_t ws_size,
                              hipStream_t stream) {
    const float* q   = (const float*)d_in[0];
    const float* k   = (const float*)d_in[1];
    const float* rpb = (const float*)d_in[2];
    float* out = (float*)d_out;

    natt_disp_kernel<<<GRID, 256, 0, stream>>>(q, k, rpb, out);
}

// Round 6
// 22.106 us; speedup vs baseline: 3.6871x; 1.0233x over previous
//
#include <hip/hip_runtime.h>

typedef _Float16 h2 __attribute__((ext_vector_type(2)));

#define DH 40
#define DW 40
#define DT 40
#define NC 96
#define NH 6
#define HD 16
#define NTOK 27
#define NVOX (DH * DW * DT)

// Tile: one head x (8 x 4 x 8) voxels, 256 threads, thread = 1 voxel.
#define TX 8
#define TY 4
#define TZ 8
#define HX 10
#define HY 6
#define HZ 10
#define NHALO (HX * HY * HZ)       // 600
#define ROW_I4 3                   // 48B row stride: 32B f16 data + 16B pad

#define TXN (DH / TX)              // 5
#define TYN (DW / TY)              // 10
#define TZN (DT / TZ)              // 5
#define NTILE (TXN * TYN * TZN)    // 250
#define NJOB (NTILE * NH)          // 1500
#define NXCD 8
#define GRID 1504
#define PER_XCD (GRID / NXCD)      // 188

__device__ __forceinline__ float dot2acc(h2 a, h2 b, float c) {
    return __builtin_amdgcn_fdot2(a, b, c, false);
}

// cvt_pkrtz returns __fp16x2; bit-cast to our _Float16x2.
__device__ __forceinline__ h2 pkrtz(float a, float b) {
    return __builtin_bit_cast(h2, __builtin_amdgcn_cvt_pkrtz(a, b));
}

union I4H {
    int4 v[2];
    h2 h[8];
};

__global__ __launch_bounds__(256) void natt_disp_kernel(
    const float* __restrict__ q,
    const float* __restrict__ k,
    const float* __restrict__ rpb,
    float* __restrict__ out)
{
    __shared__ int4 s_k[NHALO * ROW_I4];   // 28.8 KB

    // XCD swizzle: consecutive blockIdx round-robin across 8 XCDs; chunked
    // job space keeps the 6 head-blocks of a tile on one XCD's L2.
    const int job = (blockIdx.x & (NXCD - 1)) * PER_XCD + (blockIdx.x >> 3);
    if (job >= NJOB) return;   // block-uniform, before any sync

    const int h    = job % NH;
    const int tile = job / NH;
    const int tz = tile % TZN;
    const int ty = (tile / TZN) % TYN;
    const int tx = tile / (TZN * TYN);
    const int x0 = tx * TX, y0 = ty * TY, z0 = tz * TZ;

    const int tid = threadIdx.x;

    // ---- rpb: block-uniform -> scalar loads into SGPRs ----
    float rk[NTOK];
    {
        const float* rb = rpb + h * NTOK;
        #pragma unroll
        for (int kk = 0; kk < NTOK; ++kk) rk[kk] = rb[kk];
    }

    // ---- Stage k halo as f16: 600 whole-voxel jobs, 3 rounds ----
    #pragma unroll
    for (int it = 0; it < 3; ++it) {
        const int n = tid + it * 256;
        if (n < NHALO) {
            const int hx = n / (HY * HZ);
            const int r  = n - hx * (HY * HZ);
            const int hy = r / HZ;
            const int hz = r - hy * HZ;
            const int gx = x0 - 1 + hx;
            const int gy = y0 - 1 + hy;
            const int gz = z0 - 1 + hz;
            I4H u;
            u.v[0] = make_int4(0, 0, 0, 0);
            u.v[1] = make_int4(0, 0, 0, 0);
            if (((unsigned)gx < DH) & ((unsigned)gy < DW) & ((unsigned)gz < DT)) {
                const float* src = k + ((size_t)((gx * DW + gy) * DT + gz)) * NC
                                     + h * HD;
                const float4 a = *(const float4*)(src);
                const float4 b = *(const float4*)(src + 4);
                const float4 c = *(const float4*)(src + 8);
                const float4 d = *(const float4*)(src + 12);
                u.h[0] = pkrtz(a.x, a.y);
                u.h[1] = pkrtz(a.z, a.w);
                u.h[2] = pkrtz(b.x, b.y);
                u.h[3] = pkrtz(b.z, b.w);
                u.h[4] = pkrtz(c.x, c.y);
                u.h[5] = pkrtz(c.z, c.w);
                u.h[6] = pkrtz(d.x, d.y);
                u.h[7] = pkrtz(d.z, d.w);
            }
            s_k[n * ROW_I4 + 0] = u.v[0];
            s_k[n * ROW_I4 + 1] = u.v[1];
        }
    }

    // ---- q fragment direct, unscaled (scale folded into logit fma) ----
    const int lz = tid & (TZ - 1);
    const int ly = (tid >> 3) & (TY - 1);
    const int lx = tid >> 5;
    const int vox = ((x0 + lx) * DW + (y0 + ly)) * DT + (z0 + lz);

    h2 qh[8];
    {
        const float4* qv = (const float4*)(q + (size_t)vox * NC + h * HD);
        const float4 a = qv[0], b = qv[1], c = qv[2], d = qv[3];
        qh[0] = pkrtz(a.x, a.y);
        qh[1] = pkrtz(a.z, a.w);
        qh[2] = pkrtz(b.x, b.y);
        qh[3] = pkrtz(b.z, b.w);
        qh[4] = pkrtz(c.x, c.y);
        qh[5] = pkrtz(c.z, c.w);
        qh[6] = pkrtz(d.x, d.y);
        qh[7] = pkrtz(d.z, d.w);
    }

    __syncthreads();

    // ---- 27 neighbor dots (2x ds_read_b128 + 8x v_dot2 each) + rpb ----
    float l[NTOK];
    #pragma unroll
    for (int i = 0; i < 3; ++i) {
        #pragma unroll
        for (int j = 0; j < 3; ++j) {
            const int base = ((lx + i) * HY + (ly + j)) * HZ + lz;
            #pragma unroll
            for (int ll = 0; ll < 3; ++ll) {
                const int n = base + ll;
                I4H u;
                u.v[0] = s_k[n * ROW_I4 + 0];
                u.v[1] = s_k[n * ROW_I4 + 1];
                float d = 0.0f;
                d = dot2acc(qh[0], u.h[0], d);
                d = dot2acc(qh[1], u.h[1], d);
                d = dot2acc(qh[2], u.h[2], d);
                d = dot2acc(qh[3], u.h[3], d);
                d = dot2acc(qh[4], u.h[4], d);
                d = dot2acc(qh[5], u.h[5], d);
                d = dot2acc(qh[6], u.h[6], d);
                d = dot2acc(qh[7], u.h[7], d);
                const int kk = (i * 3 + j) * 3 + ll;
                l[kk] = fmaf(d, 0.25f, rk[kk]);   // scale = 16^-0.5
            }
        }
    }

    // ---- max via fmax tree (compiler fuses to v_max3) ----
    float g0 = fmaxf(fmaxf(l[0],  l[1]),  l[2]);
    float g1 = fmaxf(fmaxf(l[3],  l[4]),  l[5]);
    float g2 = fmaxf(fmaxf(l[6],  l[7]),  l[8]);
    float g3 = fmaxf(fmaxf(l[9],  l[10]), l[11]);
    float g4 = fmaxf(fmaxf(l[12], l[13]), l[14]);
    float g5 = fmaxf(fmaxf(l[15], l[16]), l[17]);
    float g6 = fmaxf(fmaxf(l[18], l[19]), l[20]);
    float g7 = fmaxf(fmaxf(l[21], l[22]), l[23]);
    float g8 = fmaxf(fmaxf(l[24], l[25]), l[26]);
    float t0 = fmaxf(fmaxf(g0, g1), g2);
    float t1 = fmaxf(fmaxf(g3, g4), g5);
    float t2 = fmaxf(fmaxf(g6, g7), g8);
    const float m = fmaxf(fmaxf(t0, t1), t2);

    // ---- exp in base-2 domain: exp(l-m) = exp2(l*log2e - m*log2e) ----
    const float LOG2E = 1.44269504f;
    const float nm2 = -m * LOG2E;
    float e[NTOK];
    #pragma unroll
    for (int kk = 0; kk < NTOK; ++kk)
        e[kk] = exp2f(fmaf(l[kk], LOG2E, nm2));

    // ---- displacement via 9 plane-partials ----
    float s[9], zp[9];
    #pragma unroll
    for (int g = 0; g < 9; ++g) {
        s[g]  = (e[g * 3] + e[g * 3 + 1]) + e[g * 3 + 2];
        zp[g] = e[g * 3 + 2] - e[g * 3];
    }
    const float sum = ((s[0] + s[1]) + (s[2] + s[3]))
                    + ((s[4] + s[5]) + (s[6] + s[7])) + s[8];
    const float szs = ((zp[0] + zp[1]) + (zp[2] + zp[3]))
                    + ((zp[4] + zp[5]) + (zp[6] + zp[7])) + zp[8];
    const float sxs = ((s[6] + s[7]) + s[8]) - ((s[0] + s[1]) + s[2]);
    const float sys = ((s[2] + s[5]) + s[8]) - ((s[0] + s[3]) + s[6]);

    const float inv = __builtin_amdgcn_rcpf(sum);

    out[((size_t)(h * 3 + 0)) * NVOX + vox] = sxs * inv;
    out[((size_t)(h * 3 + 1)) * NVOX + vox] = sys * inv;
    out[((size_t)(h * 3 + 2)) * NVOX + vox] = szs * inv;
}

extern "C" void kernel_launch(void* const* d_in, const int* in_sizes, int n_in,
                              void* d_out, int out_size, void* d_ws, size_t ws_size,
                              hipStream_t stream) {
    const float* q   = (const float*)d_in[0];
    const float* k   = (const float*)d_in[1];
    const float* rpb = (const float*)d_in[2];
    float* out = (float*)d_out;

    natt_disp_kernel<<<GRID, 256, 0, stream>>>(q, k, rpb, out);
}